// Round 3
// baseline (1226.897 us; speedup 1.0000x reference)
//
#include <hip/hip_runtime.h>
#include <math.h>

#define T_TOK 8192
#define CD 1024
#define HD 4096
#define NE 8
#define MAX_SLOTS 17408   // 16384 slots + 8*127 padding, rounded up
#define MAXM_FB 8192      // max padded rows per expert (grid sizing; early-out via meta)

#define BM 128
#define BN 128
#define BK 64             // bf16 elems per K-tile (128 B rows in LDS)

typedef __bf16 bf16x8 __attribute__((ext_vector_type(8)));
typedef float f32x4 __attribute__((ext_vector_type(4)));

__device__ __forceinline__ unsigned short f2bf(float f) {
  union { float f; unsigned int u; } v; v.f = f;
  unsigned int u = v.u;
  return (unsigned short)((u + 0x7FFFu + ((u >> 16) & 1u)) >> 16);  // RNE
}

__device__ __forceinline__ float gelu_fast(float x) {
  // tanh-form gelu rewritten as x * sigmoid(2z): same math, fewer VALU ops
  float x3 = x * x * x;
  float z = 0.7978845608028654f * (x + 0.044715f * x3);
  float ez = __expf(-2.0f * z);
  return x * __builtin_amdgcn_rcpf(1.0f + ez);
}

// async global->LDS, 16 B per lane; LDS dest = wave-uniform base + lane*16
__device__ __forceinline__ void glds16(const void* g, void* l) {
  __builtin_amdgcn_global_load_lds((__attribute__((address_space(1))) void*)g,
                                   (__attribute__((address_space(3))) void*)l,
                                   16, 0, 0);
}

// ---------------- router: fp32 logits -> softmax -> top2 -> weights ----------------
__global__ void router_kernel(const float* __restrict__ x, const float* __restrict__ gw,
                              int* __restrict__ meta, int* __restrict__ route_e,
                              float* __restrict__ route_w) {
  __shared__ float4 sgw4[NE * (CD / 4)];  // 32 KB
  const int tid = threadIdx.x;
  for (int idx = tid; idx < NE * CD / 4; idx += 256) sgw4[idx] = ((const float4*)gw)[idx];
  __syncthreads();
  const int wave = tid >> 6, lane = tid & 63;
  const int t0 = blockIdx.x * 16 + wave * 4;
#pragma unroll
  for (int tt = 0; tt < 4; tt++) {
    const int t = t0 + tt;
    const float4* xr4 = (const float4*)(x + (size_t)t * CD);
    float4 xv[4];
#pragma unroll
    for (int it = 0; it < 4; it++) xv[it] = xr4[it * 64 + lane];
    float acc[NE];
#pragma unroll
    for (int e = 0; e < NE; e++) acc[e] = 0.f;
#pragma unroll
    for (int it = 0; it < 4; it++) {
#pragma unroll
      for (int e = 0; e < NE; e++) {
        float4 g = sgw4[e * 256 + it * 64 + lane];
        acc[e] += xv[it].x * g.x + xv[it].y * g.y + xv[it].z * g.z + xv[it].w * g.w;
      }
    }
#pragma unroll
    for (int e = 0; e < NE; e++) {
      float v = acc[e];
#pragma unroll
      for (int off = 32; off > 0; off >>= 1) v += __shfl_xor(v, off);
      acc[e] = v;
    }
    if (lane == 0) {
      float mx = acc[0];
#pragma unroll
      for (int e = 1; e < NE; e++) mx = fmaxf(mx, acc[e]);
      float p[NE], s = 0.f;
#pragma unroll
      for (int e = 0; e < NE; e++) { p[e] = __expf(acc[e] - mx); s += p[e]; }
      float inv = 1.0f / s;
#pragma unroll
      for (int e = 0; e < NE; e++) p[e] *= inv;
      int i0 = 0;
#pragma unroll
      for (int e = 1; e < NE; e++) if (p[e] > p[i0]) i0 = e;  // strict >: lowest idx on tie
      int i1 = (i0 == 0) ? 1 : 0;
#pragma unroll
      for (int e = 0; e < NE; e++) if (e != i0 && p[e] > p[i1]) i1 = e;
      float den = p[i0] + p[i1] + 1e-8f;
      route_e[t * 2 + 0] = i0; route_e[t * 2 + 1] = i1;
      route_w[t * 2 + 0] = p[i0] / den; route_w[t * 2 + 1] = p[i1] / den;
      atomicAdd(&meta[i0], 1);
      atomicAdd(&meta[i1], 1);
    }
  }
}

// meta layout (ints): [0:8) cnt, [8:16) offs, [16:24) mpad, [24:32) cursor
__global__ void offsets_kernel(int* meta) {
  if (threadIdx.x == 0 && blockIdx.x == 0) {
    int off = 0;
    for (int e = 0; e < NE; e++) {
      int pc = (meta[e] + 127) & ~127;
      meta[8 + e] = off;
      meta[16 + e] = pc;
      off += pc;
    }
  }
}

__global__ void scatter_kernel(const int* __restrict__ route_e, const float* __restrict__ route_w,
                               int* __restrict__ meta, int* __restrict__ slot_token,
                               float* __restrict__ slot_w) {
  int t = blockIdx.x * 256 + threadIdx.x;
#pragma unroll
  for (int k = 0; k < 2; k++) {
    int e = route_e[t * 2 + k];
    float w = route_w[t * 2 + k];
    int idx = atomicAdd(&meta[24 + e], 1);
    int slot = meta[8 + e] + idx;
    slot_token[slot] = t;
    slot_w[slot] = w;
  }
}

__global__ void gather_kernel(const float* __restrict__ x, const int* __restrict__ slot_token,
                              unsigned short* __restrict__ xg) {
  int slot = blockIdx.x;
  int tkn = slot_token[slot];
  int i = threadIdx.x * 4;
  ushort4 o;
  if (tkn < 0) {
    o.x = 0; o.y = 0; o.z = 0; o.w = 0;
  } else {
    const float4 v = *(const float4*)(x + (size_t)tkn * CD + i);
    o.x = f2bf(v.x); o.y = f2bf(v.y); o.z = f2bf(v.z); o.w = f2bf(v.w);
  }
  *(ushort4*)(xg + (size_t)slot * CD + i) = o;
}

__global__ void cvt_kernel(const float* __restrict__ src, unsigned short* __restrict__ dst, int n4) {
  int i = blockIdx.x * 256 + threadIdx.x;
  if (i >= n4) return;
  const float4 v = *(const float4*)(src + (size_t)i * 4);
  ushort4 o;
  o.x = f2bf(v.x); o.y = f2bf(v.y); o.z = f2bf(v.z); o.w = f2bf(v.w);
  *(ushort4*)(dst + (size_t)i * 4) = o;
}

// ======================= GEMM1: h = gelu(x_g @ w1^T + b1), K = CD =======================
// 1-D grid, e = bid&7 (XCD round-robin), m fastest within expert (co-resident blocks
// share the B n-slab). Double-buffered LDS: one barrier per kt; loads for kt+1 issued
// right after the barrier and overlap compute on kt.
// XOR-swizzled LDS granules (16B): granule gg of row holds global granule gg ^ (row&7).
__global__ __launch_bounds__(256, 2)
void gemm1_kernel(const unsigned short* __restrict__ Ag,   // x_g [MAX_SLOTS][CD]
                  const unsigned short* __restrict__ Ball, // bf16 w1 [NE][HD][CD]
                  const float* __restrict__ b1,            // [NE][HD]
                  unsigned short* __restrict__ Hout,       // h [MAX_SLOTS][HD]
                  const int* __restrict__ meta) {
  const int gid = blockIdx.x;
  const int e = gid & 7;
  const int rr = gid >> 3;
  const int m_idx = rr & 63, n_idx = rr >> 6;   // m fastest
  const int mpad = meta[16 + e];
  const int m0 = m_idx * BM;
  if (m0 >= mpad) return;
  const int n0 = n_idx * BN;
  const int off = meta[8 + e];
  const unsigned short* A = Ag + (size_t)(off + m0) * CD;
  const unsigned short* B = Ball + (size_t)e * (HD * CD) + (size_t)n0 * CD;
  const float* bias = b1 + (size_t)e * HD;

  __shared__ unsigned short As[2][BM * BK];
  __shared__ unsigned short Bs[2][BN * BK];
  const int tid = threadIdx.x;
  const int lane = tid & 63, wave = tid >> 6;
  const int wm = wave >> 1, wn = wave & 1;
  const int r = lane & 15, qq = lane >> 4;
  const int lr = lane >> 3;
  const int gc = (lane & 7) ^ lr;
  const int rx = r & 7;

  f32x4 acc[4][4];
#pragma unroll
  for (int i = 0; i < 4; i++)
#pragma unroll
    for (int j = 0; j < 4; j++) acc[i][j] = 0.f;

  const int NT = CD / BK;  // 16
  // preload kt=0 into buf 0
#pragma unroll
  for (int c = 0; c < 4; c++) {
    const int rowb = wave * 32 + c * 8;
    glds16(A + (size_t)(rowb + lr) * CD + gc * 8, &As[0][rowb * BK]);
    glds16(B + (size_t)(rowb + lr) * CD + gc * 8, &Bs[0][rowb * BK]);
  }
  for (int kt = 0; kt < NT; kt++) {
    const int cur = kt & 1;
    __syncthreads();                     // drains this tile's loads; syncs all waves
    if (kt + 1 < NT) {
      const int nxt = cur ^ 1;
#pragma unroll
      for (int c = 0; c < 4; c++) {
        const int rowb = wave * 32 + c * 8;
        glds16(A + (size_t)(rowb + lr) * CD + (kt + 1) * BK + gc * 8, &As[nxt][rowb * BK]);
        glds16(B + (size_t)(rowb + lr) * CD + (kt + 1) * BK + gc * 8, &Bs[nxt][rowb * BK]);
      }
    }
#pragma unroll
    for (int s = 0; s < 2; s++) {
      bf16x8 af[4], bfr[4];
#pragma unroll
      for (int i = 0; i < 4; i++)
        af[i] = *(const bf16x8*)&As[cur][(wm * 64 + i * 16 + r) * BK + ((((s << 2) | qq) ^ rx) << 3)];
#pragma unroll
      for (int j = 0; j < 4; j++)
        bfr[j] = *(const bf16x8*)&Bs[cur][(wn * 64 + j * 16 + r) * BK + ((((s << 2) | qq) ^ rx) << 3)];
#pragma unroll
      for (int i = 0; i < 4; i++)
#pragma unroll
        for (int j = 0; j < 4; j++)
          acc[i][j] = __builtin_amdgcn_mfma_f32_16x16x32_bf16(af[i], bfr[j], acc[i][j], 0, 0, 0);
    }
  }
  // epilogue: C/D layout col = lane&15, row = quad*4 + reg; h indexed by slot
#pragma unroll
  for (int j = 0; j < 4; j++) {
    int n = n0 + wn * 64 + j * 16 + r;
    float bj = bias[n];
#pragma unroll
    for (int i = 0; i < 4; i++) {
#pragma unroll
      for (int g = 0; g < 4; g++) {
        int ml = wm * 64 + i * 16 + qq * 4 + g;
        Hout[(size_t)(off + m0 + ml) * HD + n] = f2bf(gelu_fast(acc[i][j][g] + bj));
      }
    }
  }
}

// =============== GEMM2: out[token] += w_slot * (h @ w2^T + b2), K = HD ===============
__global__ __launch_bounds__(256, 2)
void gemm2_kernel(const unsigned short* __restrict__ Hin,  // h [MAX_SLOTS][HD]
                  const unsigned short* __restrict__ Ball, // bf16 w2 [NE][CD][HD]
                  const float* __restrict__ b2,            // [NE][CD]
                  const int* __restrict__ meta,
                  const int* __restrict__ slot_token, const float* __restrict__ slot_w,
                  float* __restrict__ out) {
  const int gid = blockIdx.x;
  const int e = gid & 7;
  const int rr = gid >> 3;
  const int m_idx = rr & 63, n_idx = rr >> 6;
  const int mpad = meta[16 + e];
  const int m0 = m_idx * BM;
  if (m0 >= mpad) return;
  const int n0 = n_idx * BN;
  const int off = meta[8 + e];
  const unsigned short* A = Hin + (size_t)(off + m0) * HD;
  const unsigned short* B = Ball + (size_t)e * (CD * HD) + (size_t)n0 * HD;
  const float* bias = b2 + (size_t)e * CD;

  __shared__ unsigned short As[2][BM * BK];
  __shared__ unsigned short Bs[2][BN * BK];
  const int tid = threadIdx.x;
  const int lane = tid & 63, wave = tid >> 6;
  const int wm = wave >> 1, wn = wave & 1;
  const int r = lane & 15, qq = lane >> 4;
  const int lr = lane >> 3;
  const int gc = (lane & 7) ^ lr;
  const int rx = r & 7;

  f32x4 acc[4][4];
#pragma unroll
  for (int i = 0; i < 4; i++)
#pragma unroll
    for (int j = 0; j < 4; j++) acc[i][j] = 0.f;

  const int NT = HD / BK;  // 64
#pragma unroll
  for (int c = 0; c < 4; c++) {
    const int rowb = wave * 32 + c * 8;
    glds16(A + (size_t)(rowb + lr) * HD + gc * 8, &As[0][rowb * BK]);
    glds16(B + (size_t)(rowb + lr) * HD + gc * 8, &Bs[0][rowb * BK]);
  }
  for (int kt = 0; kt < NT; kt++) {
    const int cur = kt & 1;
    __syncthreads();
    if (kt + 1 < NT) {
      const int nxt = cur ^ 1;
#pragma unroll
      for (int c = 0; c < 4; c++) {
        const int rowb = wave * 32 + c * 8;
        glds16(A + (size_t)(rowb + lr) * HD + (kt + 1) * BK + gc * 8, &As[nxt][rowb * BK]);
        glds16(B + (size_t)(rowb + lr) * HD + (kt + 1) * BK + gc * 8, &Bs[nxt][rowb * BK]);
      }
    }
#pragma unroll
    for (int s = 0; s < 2; s++) {
      bf16x8 af[4], bfr[4];
#pragma unroll
      for (int i = 0; i < 4; i++)
        af[i] = *(const bf16x8*)&As[cur][(wm * 64 + i * 16 + r) * BK + ((((s << 2) | qq) ^ rx) << 3)];
#pragma unroll
      for (int j = 0; j < 4; j++)
        bfr[j] = *(const bf16x8*)&Bs[cur][(wn * 64 + j * 16 + r) * BK + ((((s << 2) | qq) ^ rx) << 3)];
#pragma unroll
      for (int i = 0; i < 4; i++)
#pragma unroll
        for (int j = 0; j < 4; j++)
          acc[i][j] = __builtin_amdgcn_mfma_f32_16x16x32_bf16(af[i], bfr[j], acc[i][j], 0, 0, 0);
    }
  }
#pragma unroll
  for (int i = 0; i < 4; i++) {
#pragma unroll
    for (int g = 0; g < 4; g++) {
      int ml = wm * 64 + i * 16 + qq * 4 + g;
      int slot = off + m0 + ml;
      int tkn = slot_token[slot];
      if (tkn < 0) continue;
      float wgt = slot_w[slot];
      float* orow = out + (size_t)tkn * CD;
#pragma unroll
      for (int j = 0; j < 4; j++) {
        int n = n0 + wn * 64 + j * 16 + r;
        atomicAdd(&orow[n], wgt * (acc[i][j][g] + bias[n]));
      }
    }
  }
}

extern "C" void kernel_launch(void* const* d_in, const int* in_sizes, int n_in,
                              void* d_out, int out_size, void* d_ws, size_t ws_size,
                              hipStream_t stream) {
  const float* x  = (const float*)d_in[0];
  const float* gw = (const float*)d_in[1];
  const float* w1 = (const float*)d_in[2];
  const float* b1 = (const float*)d_in[3];
  const float* w2 = (const float*)d_in[4];
  const float* b2 = (const float*)d_in[5];
  float* out = (float*)d_out;

  char* p = (char*)d_ws;
  size_t o = 0;
  int* meta = (int*)p;                   o = 256;
  int* slot_token = (int*)(p + o);       o += (size_t)MAX_SLOTS * 4;
  float* slot_w = (float*)(p + o);       o += (size_t)MAX_SLOTS * 4;
  int* route_e = (int*)(p + o);          o += (size_t)T_TOK * 8;
  float* route_w = (float*)(p + o);      o += (size_t)T_TOK * 8;
  o = (o + 255) & ~(size_t)255;
  unsigned short* xg  = (unsigned short*)(p + o); o += (size_t)MAX_SLOTS * CD * 2;
  unsigned short* w1b = (unsigned short*)(p + o); o += (size_t)NE * HD * CD * 2;
  unsigned short* w2b = (unsigned short*)(p + o); o += (size_t)NE * CD * HD * 2;
  unsigned short* h   = (unsigned short*)(p + o); o += (size_t)MAX_SLOTS * HD * 2;
  if (ws_size < o) return;  // workspace too small: fail validation cleanly

  hipMemsetAsync(meta, 0, 256, stream);
  hipMemsetAsync(slot_token, 0xFF, (size_t)MAX_SLOTS * 4, stream);  // -1
  hipMemsetAsync(out, 0, (size_t)out_size * 4, stream);

  router_kernel<<<T_TOK / 16, 256, 0, stream>>>(x, gw, meta, route_e, route_w);
  offsets_kernel<<<1, 64, 0, stream>>>(meta);
  scatter_kernel<<<T_TOK / 256, 256, 0, stream>>>(route_e, route_w, meta, slot_token, slot_w);
  gather_kernel<<<MAX_SLOTS, 256, 0, stream>>>(x, slot_token, xg);

  const int n4w = NE * HD * CD / 4;
  cvt_kernel<<<n4w / 256, 256, 0, stream>>>(w1, w1b, n4w);
  cvt_kernel<<<n4w / 256, 256, 0, stream>>>(w2, w2b, n4w);

  // 1-D grids: e = bid&7, then m fastest, n slowest
  gemm1_kernel<<<NE * (MAXM_FB / BM) * (HD / BN), 256, 0, stream>>>(xg, w1b, b1, h, meta);
  gemm2_kernel<<<NE * (MAXM_FB / BM) * (CD / BN), 256, 0, stream>>>(h, w2b, b2, meta,
                                                                    slot_token, slot_w, out);
}

// Round 4
// 1041.292 us; speedup vs baseline: 1.1782x; 1.1782x over previous
//
#include <hip/hip_runtime.h>
#include <math.h>

#define T_TOK 8192
#define CD 1024
#define HD 4096
#define NE 8
#define MAX_SLOTS 18432   // 16384 + 8*255 pad, rounded up
#define MROWS 16384       // worst-case rows per expert
#define MB_SLOTS 64       // MROWS/256 m-block slots per expert

#define BM 256
#define BN 256
#define BK 64

typedef __bf16 bf16x8 __attribute__((ext_vector_type(8)));
typedef float f32x4 __attribute__((ext_vector_type(4)));

__device__ __forceinline__ unsigned short f2bf(float f) {
  union { float f; unsigned int u; } v; v.f = f;
  unsigned int u = v.u;
  return (unsigned short)((u + 0x7FFFu + ((u >> 16) & 1u)) >> 16);  // RNE
}

__device__ __forceinline__ float gelu_fast(float x) {
  // tanh-form gelu as x * sigmoid(2z)
  float x3 = x * x * x;
  float z = 0.7978845608028654f * (x + 0.044715f * x3);
  float ez = __expf(-2.0f * z);
  return x * __builtin_amdgcn_rcpf(1.0f + ez);
}

__device__ __forceinline__ void glds16(const void* g, void* l) {
  __builtin_amdgcn_global_load_lds((__attribute__((address_space(1))) void*)g,
                                   (__attribute__((address_space(3))) void*)l,
                                   16, 0, 0);
}

// ---------------- router ----------------
__global__ void router_kernel(const float* __restrict__ x, const float* __restrict__ gw,
                              int* __restrict__ meta, int* __restrict__ route_e,
                              float* __restrict__ route_w) {
  __shared__ float4 sgw4[NE * (CD / 4)];  // 32 KB
  __shared__ int hist[NE];
  const int tid = threadIdx.x;
  for (int idx = tid; idx < NE * CD / 4; idx += 256) sgw4[idx] = ((const float4*)gw)[idx];
  if (tid < NE) hist[tid] = 0;
  __syncthreads();
  const int wave = tid >> 6, lane = tid & 63;
  const int t0 = blockIdx.x * 16 + wave * 4;
#pragma unroll
  for (int tt = 0; tt < 4; tt++) {
    const int t = t0 + tt;
    const float4* xr4 = (const float4*)(x + (size_t)t * CD);
    float4 xv[4];
#pragma unroll
    for (int it = 0; it < 4; it++) xv[it] = xr4[it * 64 + lane];
    float acc[NE];
#pragma unroll
    for (int e = 0; e < NE; e++) acc[e] = 0.f;
#pragma unroll
    for (int it = 0; it < 4; it++) {
#pragma unroll
      for (int e = 0; e < NE; e++) {
        float4 g = sgw4[e * 256 + it * 64 + lane];
        acc[e] += xv[it].x * g.x + xv[it].y * g.y + xv[it].z * g.z + xv[it].w * g.w;
      }
    }
#pragma unroll
    for (int e = 0; e < NE; e++) {
      float v = acc[e];
#pragma unroll
      for (int off = 32; off > 0; off >>= 1) v += __shfl_xor(v, off);
      acc[e] = v;
    }
    if (lane == 0) {
      float mx = acc[0];
#pragma unroll
      for (int e = 1; e < NE; e++) mx = fmaxf(mx, acc[e]);
      float p[NE], s = 0.f;
#pragma unroll
      for (int e = 0; e < NE; e++) { p[e] = __expf(acc[e] - mx); s += p[e]; }
      float inv = 1.0f / s;
#pragma unroll
      for (int e = 0; e < NE; e++) p[e] *= inv;
      int i0 = 0;
#pragma unroll
      for (int e = 1; e < NE; e++) if (p[e] > p[i0]) i0 = e;  // strict >: lowest idx on tie
      int i1 = (i0 == 0) ? 1 : 0;
#pragma unroll
      for (int e = 0; e < NE; e++) if (e != i0 && p[e] > p[i1]) i1 = e;
      float den = p[i0] + p[i1] + 1e-8f;
      route_e[t * 2 + 0] = i0; route_e[t * 2 + 1] = i1;
      route_w[t * 2 + 0] = p[i0] / den; route_w[t * 2 + 1] = p[i1] / den;
      atomicAdd(&hist[i0], 1);
      atomicAdd(&hist[i1], 1);
    }
  }
  __syncthreads();
  if (tid < NE && hist[tid] > 0) atomicAdd(&meta[tid], hist[tid]);
}

// meta: [0:8) cnt, [8:16) offs, [16:24) mpad, [24:32) cursor
__global__ void offsets_kernel(int* meta) {
  if (threadIdx.x == 0 && blockIdx.x == 0) {
    int off = 0;
    for (int e = 0; e < NE; e++) {
      int pc = (meta[e] + 255) & ~255;   // pad to 256 rows
      meta[8 + e] = off;
      meta[16 + e] = pc;
      off += pc;
    }
  }
}

__global__ void scatter_kernel(const int* __restrict__ route_e, const float* __restrict__ route_w,
                               int* __restrict__ meta, int* __restrict__ slot_token,
                               float* __restrict__ slot_w) {
  __shared__ int hist[NE], base[NE];
  const int tid = threadIdx.x;
  const int t = blockIdx.x * 256 + tid;
  if (tid < NE) hist[tid] = 0;
  __syncthreads();
  int e0 = route_e[t * 2 + 0], e1 = route_e[t * 2 + 1];
  float w0 = route_w[t * 2 + 0], w1v = route_w[t * 2 + 1];
  int lr0 = atomicAdd(&hist[e0], 1);
  int lr1 = atomicAdd(&hist[e1], 1);
  __syncthreads();
  if (tid < NE) base[tid] = (hist[tid] > 0) ? atomicAdd(&meta[24 + tid], hist[tid]) : 0;
  __syncthreads();
  int s0 = meta[8 + e0] + base[e0] + lr0;
  int s1 = meta[8 + e1] + base[e1] + lr1;
  slot_token[s0] = t; slot_w[s0] = w0;
  slot_token[s1] = t; slot_w[s1] = w1v;
}

__global__ void gather_kernel(const float* __restrict__ x, const int* __restrict__ slot_token,
                              unsigned short* __restrict__ xg) {
  int slot = blockIdx.x;
  int tkn = slot_token[slot];
  int i = threadIdx.x * 4;
  ushort4 o;
  if (tkn < 0) {
    o.x = 0; o.y = 0; o.z = 0; o.w = 0;
  } else {
    const float4 v = *(const float4*)(x + (size_t)tkn * CD + i);
    o.x = f2bf(v.x); o.y = f2bf(v.y); o.z = f2bf(v.z); o.w = f2bf(v.w);
  }
  *(ushort4*)(xg + (size_t)slot * CD + i) = o;
}

__global__ void cvt_kernel(const float* __restrict__ src, unsigned short* __restrict__ dst, int n4) {
  int i = blockIdx.x * 256 + threadIdx.x;
  if (i >= n4) return;
  const float4 v = *(const float4*)(src + (size_t)i * 4);
  ushort4 o;
  o.x = f2bf(v.x); o.y = f2bf(v.y); o.z = f2bf(v.z); o.w = f2bf(v.w);
  *(ushort4*)(dst + (size_t)i * 4) = o;
}

// ======================= GEMM1: h = gelu(x_g @ w1^T + b1), K=CD =======================
// 256x256 tile, 512 threads (8 waves, 4 wm x 2 wn, per-wave 64x128). Single 64 KB LDS
// buffer, m97 2-barrier K-loop. XOR-swizzled 16B granules. Supertile 4x4 dispatch order
// within XCD-pinned expert (L2 window = 8 slabs x 512 KB = 4 MB).
__global__ __launch_bounds__(512, 2)
void gemm1_kernel(const unsigned short* __restrict__ Ag,   // x_g [MAX_SLOTS][CD]
                  const unsigned short* __restrict__ W1,   // bf16 w1 [NE][HD][CD]
                  const float* __restrict__ b1,            // [NE][HD]
                  unsigned short* __restrict__ Hout,       // h [MAX_SLOTS][HD]
                  const int* __restrict__ meta) {
  const int gid = blockIdx.x;
  const int e = gid & 7;
  const int rr = gid >> 3;                 // [0, 1024): 64 m-slots x 16 n
  const int sup = rr >> 4;                 // 16 msup x 4 nsup, msup fastest
  const int mi = rr & 3, ni = (rr >> 2) & 3;
  const int m_idx = (sup & 15) * 4 + mi;
  const int n_idx = (sup >> 4) * 4 + ni;
  const int mpad = meta[16 + e];
  const int m0 = m_idx * BM;
  if (m0 >= mpad) return;
  const int n0 = n_idx * BN;
  const int off = meta[8 + e];
  const unsigned short* A = Ag + (size_t)(off + m0) * CD;
  const unsigned short* B = W1 + (size_t)e * (HD * CD) + (size_t)n0 * CD;
  const float* bias = b1 + (size_t)e * HD;

  __shared__ unsigned short As[BM * BK];   // 32 KB
  __shared__ unsigned short Bs[BN * BK];   // 32 KB
  const int tid = threadIdx.x;
  const int lane = tid & 63, wave = tid >> 6;
  const int wm = wave >> 1, wn = wave & 1;
  const int r = lane & 15, qq = lane >> 4;
  const int lr = lane >> 3;
  const int gc = (lane & 7) ^ lr;
  const int rx = r & 7;

  f32x4 acc[4][8];
#pragma unroll
  for (int i = 0; i < 4; i++)
#pragma unroll
    for (int j = 0; j < 8; j++) acc[i][j] = 0.f;

  for (int kt = 0; kt < CD / BK; kt++) {
#pragma unroll
    for (int c = 0; c < 4; c++) {
      const int rowb = wave * 32 + c * 8;
      glds16(A + (size_t)(rowb + lr) * CD + kt * BK + gc * 8, &As[rowb * BK]);
      glds16(B + (size_t)(rowb + lr) * CD + kt * BK + gc * 8, &Bs[rowb * BK]);
    }
    __syncthreads();
#pragma unroll
    for (int s = 0; s < 2; s++) {
      const int go = (((s << 2) | qq) ^ rx) << 3;
      bf16x8 af[4], bfr[8];
#pragma unroll
      for (int i = 0; i < 4; i++)
        af[i] = *(const bf16x8*)&As[(wm * 64 + i * 16 + r) * BK + go];
#pragma unroll
      for (int j = 0; j < 8; j++)
        bfr[j] = *(const bf16x8*)&Bs[(wn * 128 + j * 16 + r) * BK + go];
#pragma unroll
      for (int i = 0; i < 4; i++)
#pragma unroll
        for (int j = 0; j < 8; j++)
          acc[i][j] = __builtin_amdgcn_mfma_f32_16x16x32_bf16(af[i], bfr[j], acc[i][j], 0, 0, 0);
    }
    __syncthreads();
  }
  // epilogue: C/D col = lane&15, row = quad*4 + reg
#pragma unroll
  for (int j = 0; j < 8; j++) {
    int n = n0 + wn * 128 + j * 16 + r;
    float bj = bias[n];
#pragma unroll
    for (int i = 0; i < 4; i++) {
#pragma unroll
      for (int g = 0; g < 4; g++) {
        int ml = wm * 64 + i * 16 + qq * 4 + g;
        Hout[(size_t)(off + m0 + ml) * HD + n] = f2bf(gelu_fast(acc[i][j][g] + bj));
      }
    }
  }
}

// ========== GEMM2: out[token] += w_slot * (h @ w2^T + b2), K=HD, split-K=2 ==========
__global__ __launch_bounds__(512, 2)
void gemm2_kernel(const unsigned short* __restrict__ Hin,  // h [MAX_SLOTS][HD]
                  const unsigned short* __restrict__ W2,   // bf16 w2 [NE][CD][HD]
                  const float* __restrict__ b2,            // [NE][CD]
                  const int* __restrict__ meta,
                  const int* __restrict__ slot_token, const float* __restrict__ slot_w,
                  float* __restrict__ out) {
  const int gid = blockIdx.x;
  const int e = gid & 7;
  const int rr = gid >> 3;                 // [0, 512): ks x (64 m x 4 n)
  const int ks = rr >> 8;
  const int r2 = rr & 255;
  const int sup = r2 >> 2;                 // 32 msup x 2 nsup, msup fastest
  const int mi = r2 & 1, ni = (r2 >> 1) & 1;
  const int m_idx = (sup & 31) * 2 + mi;
  const int n_idx = (sup >> 5) * 2 + ni;
  const int mpad = meta[16 + e];
  const int m0 = m_idx * BM;
  if (m0 >= mpad) return;
  const int n0 = n_idx * BN;
  const int off = meta[8 + e];
  const int k0 = ks * (HD / 2);
  const unsigned short* A = Hin + (size_t)(off + m0) * HD + k0;
  const unsigned short* B = W2 + (size_t)e * (CD * HD) + (size_t)n0 * HD + k0;
  const float* bias = b2 + (size_t)e * CD;

  __shared__ unsigned short As[BM * BK];
  __shared__ unsigned short Bs[BN * BK];
  const int tid = threadIdx.x;
  const int lane = tid & 63, wave = tid >> 6;
  const int wm = wave >> 1, wn = wave & 1;
  const int r = lane & 15, qq = lane >> 4;
  const int lr = lane >> 3;
  const int gc = (lane & 7) ^ lr;
  const int rx = r & 7;

  f32x4 acc[4][8];
#pragma unroll
  for (int i = 0; i < 4; i++)
#pragma unroll
    for (int j = 0; j < 8; j++) acc[i][j] = 0.f;

  for (int kt = 0; kt < (HD / 2) / BK; kt++) {
#pragma unroll
    for (int c = 0; c < 4; c++) {
      const int rowb = wave * 32 + c * 8;
      glds16(A + (size_t)(rowb + lr) * HD + kt * BK + gc * 8, &As[rowb * BK]);
      glds16(B + (size_t)(rowb + lr) * HD + kt * BK + gc * 8, &Bs[rowb * BK]);
    }
    __syncthreads();
#pragma unroll
    for (int s = 0; s < 2; s++) {
      const int go = (((s << 2) | qq) ^ rx) << 3;
      bf16x8 af[4], bfr[8];
#pragma unroll
      for (int i = 0; i < 4; i++)
        af[i] = *(const bf16x8*)&As[(wm * 64 + i * 16 + r) * BK + go];
#pragma unroll
      for (int j = 0; j < 8; j++)
        bfr[j] = *(const bf16x8*)&Bs[(wn * 128 + j * 16 + r) * BK + go];
#pragma unroll
      for (int i = 0; i < 4; i++)
#pragma unroll
        for (int j = 0; j < 8; j++)
          acc[i][j] = __builtin_amdgcn_mfma_f32_16x16x32_bf16(af[i], bfr[j], acc[i][j], 0, 0, 0);
    }
    __syncthreads();
  }
#pragma unroll
  for (int i = 0; i < 4; i++) {
#pragma unroll
    for (int g = 0; g < 4; g++) {
      int ml = wm * 64 + i * 16 + qq * 4 + g;
      int slot = off + m0 + ml;
      int tkn = slot_token[slot];
      if (tkn < 0) continue;
      float wgt = slot_w[slot];
      float* orow = out + (size_t)tkn * CD;
#pragma unroll
      for (int j = 0; j < 8; j++) {
        int n = n0 + wn * 128 + j * 16 + r;
        float bj = (ks == 0) ? bias[n] : 0.0f;
        atomicAdd(&orow[n], wgt * (acc[i][j][g] + bj));
      }
    }
  }
}

extern "C" void kernel_launch(void* const* d_in, const int* in_sizes, int n_in,
                              void* d_out, int out_size, void* d_ws, size_t ws_size,
                              hipStream_t stream) {
  const float* x  = (const float*)d_in[0];
  const float* gw = (const float*)d_in[1];
  const float* w1 = (const float*)d_in[2];
  const float* b1 = (const float*)d_in[3];
  const float* w2 = (const float*)d_in[4];
  const float* b2 = (const float*)d_in[5];
  float* out = (float*)d_out;

  char* p = (char*)d_ws;
  size_t o = 0;
  int* meta = (int*)p;                   o = 256;
  int* slot_token = (int*)(p + o);       o += (size_t)MAX_SLOTS * 4;
  float* slot_w = (float*)(p + o);       o += (size_t)MAX_SLOTS * 4;
  int* route_e = (int*)(p + o);          o += (size_t)T_TOK * 8;
  float* route_w = (float*)(p + o);      o += (size_t)T_TOK * 8;
  o = (o + 255) & ~(size_t)255;
  unsigned short* xg  = (unsigned short*)(p + o); o += (size_t)MAX_SLOTS * CD * 2;
  unsigned short* w1b = (unsigned short*)(p + o); o += (size_t)NE * HD * CD * 2;
  unsigned short* w2b = (unsigned short*)(p + o); o += (size_t)NE * CD * HD * 2;
  unsigned short* h   = (unsigned short*)(p + o); o += (size_t)MAX_SLOTS * HD * 2;
  if (ws_size < o) return;  // fail cleanly if workspace too small

  hipMemsetAsync(meta, 0, 256, stream);
  hipMemsetAsync(slot_token, 0xFF, (size_t)MAX_SLOTS * 4, stream);  // -1
  hipMemsetAsync(out, 0, (size_t)out_size * 4, stream);

  router_kernel<<<T_TOK / 16, 256, 0, stream>>>(x, gw, meta, route_e, route_w);
  offsets_kernel<<<1, 64, 0, stream>>>(meta);
  scatter_kernel<<<T_TOK / 256, 256, 0, stream>>>(route_e, route_w, meta, slot_token, slot_w);
  gather_kernel<<<MAX_SLOTS, 256, 0, stream>>>(x, slot_token, xg);

  const int n4w = NE * HD * CD / 4;
  cvt_kernel<<<n4w / 256, 256, 0, stream>>>(w1, w1b, n4w);
  cvt_kernel<<<n4w / 256, 256, 0, stream>>>(w2, w2b, n4w);

  // gemm1: 8 experts x (64 m-slots x 16 n) ; gemm2: 8 x (2 ks x 64 m x 4 n)
  gemm1_kernel<<<NE * MB_SLOTS * (HD / BN), 512, 0, stream>>>(xg, w1b, b1, h, meta);
  gemm2_kernel<<<NE * 2 * MB_SLOTS * (CD / BN), 512, 0, stream>>>(h, w2b, b2, meta,
                                                                  slot_token, slot_w, out);
}